// Round 1
// baseline (997.975 us; speedup 1.0000x reference)
//
#include <hip/hip_runtime.h>
#include <cstddef>

typedef float f32x4 __attribute__((ext_vector_type(4)));
typedef __bf16 bf16x8 __attribute__((ext_vector_type(8)));
typedef unsigned short u16x8 __attribute__((ext_vector_type(8)));
typedef unsigned short u16x4 __attribute__((ext_vector_type(4)));

constexpr int NB = 2, S = 4096, H = 16, D = 128;
constexpr int DIN = 2048, NQKV = 6144, HD = 2048;
constexpr int BLK = 256, NBL = 16;

constexpr size_t SZ_XB    = (size_t)NB * S * DIN * 2;       // 33.5 MB
constexpr size_t SZ_WQKVT = (size_t)NQKV * DIN * 2;         // 25.2 MB
constexpr size_t SZ_WGT   = (size_t)HD * DIN * 2;           //  8.4 MB
constexpr size_t SZ_WOUTT = (size_t)HD * HD * 2;            //  8.4 MB
constexpr size_t SZ_QKVB  = (size_t)NB * S * NQKV * 2;      // 100.7 MB
constexpr size_t SZ_GB    = (size_t)NB * S * HD * 2;        // 33.5 MB
constexpr size_t SZ_ST    = (size_t)NB * H * NBL * D * D * 2; // 16.8 MB
constexpr size_t SZ_OB    = (size_t)NB * S * HD * 2;        // 33.5 MB

__device__ __forceinline__ float bf2f(unsigned short u) {
  return __uint_as_float(((unsigned)u) << 16);
}
__device__ __forceinline__ unsigned short f2bf(float f) {
  unsigned u = __float_as_uint(f);
  u += 0x7fffu + ((u >> 16) & 1u);
  return (unsigned short)(u >> 16);
}

// ---------------- fp32 -> bf16 elementwise convert (8 elems/thread) --------
__global__ __launch_bounds__(256) void cvt_bf16(
    const float* __restrict__ in, unsigned short* __restrict__ out) {
  const size_t id = (size_t)blockIdx.x * 256 + threadIdx.x;
  const float4 a = *(const float4*)&in[id * 8];
  const float4 c = *(const float4*)&in[id * 8 + 4];
  u16x8 o;
  o[0] = f2bf(a.x); o[1] = f2bf(a.y); o[2] = f2bf(a.z); o[3] = f2bf(a.w);
  o[4] = f2bf(c.x); o[5] = f2bf(c.y); o[6] = f2bf(c.z); o[7] = f2bf(c.w);
  *(u16x8*)&out[id * 8] = o;
}

// ---------------- W[K][N] f32  ->  Wt[N][K] bf16 (32x32 LDS tiles) ---------
__global__ __launch_bounds__(256) void transpose_cvt(
    const float* __restrict__ W, unsigned short* __restrict__ Wt, int K, int N) {
  __shared__ unsigned short tile[32][33];
  const int n0 = blockIdx.x * 32, k0 = blockIdx.y * 32;
  const int t = threadIdx.x;
  const int r = t >> 3, c4 = (t & 7) * 4;
  const float4 v = *(const float4*)&W[(size_t)(k0 + r) * N + n0 + c4];
  tile[r][c4 + 0] = f2bf(v.x);
  tile[r][c4 + 1] = f2bf(v.y);
  tile[r][c4 + 2] = f2bf(v.z);
  tile[r][c4 + 3] = f2bf(v.w);
  __syncthreads();
  u16x4 o;
  #pragma unroll
  for (int i = 0; i < 4; ++i) o[i] = tile[c4 + i][r];
  *(u16x4*)&Wt[(size_t)(n0 + r) * K + k0 + c4] = o;
}

// ---------------- bf16 MFMA GEMM: C = act(A @ Bt^T) ------------------------
// A [M][K] bf16 row-major, Bt [N][K] bf16 row-major (pre-transposed weight).
// 128x128 tile, BK=64, 4 waves of 64x64. ACT: 0 none->f32, 1 silu->bf16,
// 2 sigmoid->bf16.
template<int ACT>
__global__ __launch_bounds__(256) void gemm_bt(
    const unsigned short* __restrict__ A, const unsigned short* __restrict__ Bt,
    void* __restrict__ C, int M, int N, int K) {
  __shared__ unsigned short Al[128][72];
  __shared__ unsigned short Bl[128][72];
  const int t = threadIdx.x;
  const int bn = blockIdx.x, bm = blockIdx.y;
  const int lane = t & 63, wave = t >> 6, wr = wave >> 1, wc = wave & 1;
  f32x4 acc[4][4] = {};
  const int sr = t >> 3, sc = (t & 7) * 8;
  for (int k0 = 0; k0 < K; k0 += 64) {
    if (k0) __syncthreads();
    #pragma unroll
    for (int p = 0; p < 4; ++p) {
      const int r = sr + p * 32;
      *(u16x8*)&Al[r][sc] = *(const u16x8*)&A[(size_t)(bm * 128 + r) * K + k0 + sc];
      *(u16x8*)&Bl[r][sc] = *(const u16x8*)&Bt[(size_t)(bn * 128 + r) * K + k0 + sc];
    }
    __syncthreads();
    #pragma unroll
    for (int kk = 0; kk < 2; ++kk) {
      bf16x8 af[4], bfr[4];
      #pragma unroll
      for (int m = 0; m < 4; ++m)
        af[m] = *(const bf16x8*)&Al[wr * 64 + m * 16 + (lane & 15)][kk * 32 + (lane >> 4) * 8];
      #pragma unroll
      for (int n = 0; n < 4; ++n)
        bfr[n] = *(const bf16x8*)&Bl[wc * 64 + n * 16 + (lane & 15)][kk * 32 + (lane >> 4) * 8];
      #pragma unroll
      for (int m = 0; m < 4; ++m)
        #pragma unroll
        for (int n = 0; n < 4; ++n)
          acc[m][n] = __builtin_amdgcn_mfma_f32_16x16x32_bf16(af[m], bfr[n], acc[m][n], 0, 0, 0);
    }
  }
  // epilogue: C/D layout col = lane&15, row = (lane>>4)*4 + reg  [m89-verified]
  const int ro = (lane >> 4) * 4, co = lane & 15;
  #pragma unroll
  for (int m = 0; m < 4; ++m)
    #pragma unroll
    for (int n = 0; n < 4; ++n) {
      const int gc = bn * 128 + wc * 64 + n * 16 + co;
      #pragma unroll
      for (int r = 0; r < 4; ++r) {
        const int gr = bm * 128 + wr * 64 + m * 16 + ro + r;
        float v = acc[m][n][r];
        if constexpr (ACT == 1) v = v / (1.f + __expf(-v));     // silu
        if constexpr (ACT == 2) v = 1.f / (1.f + __expf(-v));   // sigmoid
        if constexpr (ACT == 0) ((float*)C)[(size_t)gr * N + gc] = v;
        else ((unsigned short*)C)[(size_t)gr * N + gc] = f2bf(v);
      }
    }
}

// ---------------- per-block KV outer product: M_j = (k .* kdecay)^T @ v ----
// grid = (b*H + h)*NBL + j ; output st[(bh*NBL+j)][e][f] bf16
__global__ __launch_bounds__(256) void kv_outer(
    const unsigned short* __restrict__ qkv, unsigned short* __restrict__ st) {
  const int gid = blockIdx.x;
  const int j = gid & 15;
  const int bh = gid >> 4;
  const int h = bh & 15;
  const int b = bh >> 4;
  const float slope = exp2f(-0.5f * (float)(h + 1));
  const int t = threadIdx.x;
  __shared__ unsigned short kl[64][136];
  __shared__ unsigned short vl[64][136];
  float acc[8][8] = {};
  const int e0 = (t >> 4) * 8, f0 = (t & 15) * 8;
  for (int ch = 0; ch < 4; ++ch) {
    if (ch) __syncthreads();
    #pragma unroll
    for (int i = 0; i < 4; ++i) {
      const int cc = t + 256 * i;
      const int r = cc >> 4, c0 = (cc & 15) * 8;
      const int mb = ch * 64 + r;
      const int seq = b * S + j * BLK + mb;
      const u16x8 k8 = *(const u16x8*)&qkv[(size_t)seq * NQKV + h * 384 + 128 + c0];
      const float kd = expf(-slope * (float)(255 - mb));  // exp(-slope*(BLK-arr))
      u16x8 kw;
      #pragma unroll
      for (int q2 = 0; q2 < 8; ++q2) kw[q2] = f2bf(bf2f(k8[q2]) * kd);
      *(u16x8*)&kl[r][c0] = kw;
      *(u16x8*)&vl[r][c0] = *(const u16x8*)&qkv[(size_t)seq * NQKV + h * 384 + 256 + c0];
    }
    __syncthreads();
    for (int m = 0; m < 64; ++m) {
      const u16x8 k8 = *(const u16x8*)&kl[m][e0];
      const u16x8 v8 = *(const u16x8*)&vl[m][f0];
      float kf[8], vf[8];
      #pragma unroll
      for (int q2 = 0; q2 < 8; ++q2) { kf[q2] = bf2f(k8[q2]); vf[q2] = bf2f(v8[q2]); }
      #pragma unroll
      for (int i = 0; i < 8; ++i)
        #pragma unroll
        for (int q2 = 0; q2 < 8; ++q2) acc[i][q2] += kf[i] * vf[q2];
    }
  }
  const size_t base = (size_t)gid * (D * D);
  #pragma unroll
  for (int i = 0; i < 8; ++i) {
    u16x8 ow;
    #pragma unroll
    for (int q2 = 0; q2 < 8; ++q2) ow[q2] = f2bf(acc[i][q2]);
    *(u16x8*)&st[base + (size_t)(e0 + i) * D + f0] = ow;
  }
}

// ---------------- exclusive decay scan over blocks (per element) -----------
__global__ __launch_bounds__(256) void kv_scan(unsigned short* __restrict__ st) {
  const int id = blockIdx.x * 256 + threadIdx.x;  // NB*H*D*D threads
  const int ef = id & (D * D - 1);
  const int bh = id >> 14;
  const int h = bh & 15;
  const float slope = exp2f(-0.5f * (float)(h + 1));
  const float bd = expf(-slope * 256.f);
  unsigned short* p = st + (size_t)bh * NBL * D * D + ef;
  float cur = 0.f;
  #pragma unroll
  for (int jj = 0; jj < NBL; ++jj) {
    const float m = bf2f(p[(size_t)jj * D * D]);
    p[(size_t)jj * D * D] = f2bf(cur);     // state BEFORE block jj
    cur = bd * cur + m;
  }
}

// ---------------- main attention: out = qdecay.*(q@kv) + (qk.*dd)@v --------
// grid = ((b*H+h)*NBL + j)*2 + half ; each WG does 128 q-rows x 128 dims.
__global__ __launch_bounds__(256) void attn_main(
    const unsigned short* __restrict__ qkv, const unsigned short* __restrict__ st,
    unsigned short* __restrict__ ob) {
  const int gid = blockIdx.x;
  const int half = gid & 1;
  const int rest = gid >> 1;
  const int j = rest & 15;
  const int bh = rest >> 4;
  const int h = bh & 15;
  const int b = bh >> 4;
  const float slope = exp2f(-0.5f * (float)(h + 1));
  const int t = threadIdx.x;

  __shared__ unsigned short ql[128][136];
  __shared__ unsigned short cb[64][136];   // shared chunk buffer: kv / k / v
  __shared__ unsigned short pl[128][72];   // decayed P chunk (bf16)

  #pragma unroll
  for (int i = 0; i < 8; ++i) {            // stage raw q (128x128)
    const int cc = t + 256 * i;
    const int r = cc >> 4, c0 = (cc & 15) * 8;
    const int seq = b * S + j * BLK + half * 128 + r;
    *(u16x8*)&ql[r][c0] = *(const u16x8*)&qkv[(size_t)seq * NQKV + h * 384 + c0];
  }

  float acc[8][8] = {};
  const int m0 = (t >> 4) * 8, f0 = (t & 15) * 8;
  const size_t stbase = (size_t)rest * (D * D);

  // ---- non-diagonal: raw q @ kv, qdecay factored out ----
  for (int ec = 0; ec < 2; ++ec) {
    __syncthreads();
    #pragma unroll
    for (int i = 0; i < 4; ++i) {
      const int cc = t + 256 * i;
      const int r = cc >> 4, c0 = (cc & 15) * 8;
      *(u16x8*)&cb[r][c0] = *(const u16x8*)&st[stbase + (size_t)(ec * 64 + r) * D + c0];
    }
    __syncthreads();
    for (int eo = 0; eo < 8; ++eo) {
      u16x8 qreg[8];
      #pragma unroll
      for (int i = 0; i < 8; ++i) qreg[i] = *(const u16x8*)&ql[m0 + i][ec * 64 + eo * 8];
      #pragma unroll
      for (int ee = 0; ee < 8; ++ee) {
        const u16x8 kvv = *(const u16x8*)&cb[eo * 8 + ee][f0];
        float vf[8];
        #pragma unroll
        for (int q2 = 0; q2 < 8; ++q2) vf[q2] = bf2f(kvv[q2]);
        #pragma unroll
        for (int i = 0; i < 8; ++i) {
          const float qv = bf2f(qreg[i][ee]);
          #pragma unroll
          for (int q2 = 0; q2 < 8; ++q2) acc[i][q2] += qv * vf[q2];
        }
      }
    }
  }
  #pragma unroll
  for (int i = 0; i < 8; ++i) {            // apply q_decay = exp(-slope*arr)
    const float qd = expf(-slope * (float)(half * 128 + m0 + i + 1));
    #pragma unroll
    for (int q2 = 0; q2 < 8; ++q2) acc[i][q2] *= qd;
  }

  // ---- diagonal (intra-block causal) ----
  const int nch = 2 + 2 * half;            // m' chunks of 64 needed (causal)
  const int tq = t >> 3, tp = t & 7;
  for (int c = 0; c < nch; ++c) {
    __syncthreads();
    #pragma unroll
    for (int i = 0; i < 4; ++i) {          // stage k chunk
      const int cc = t + 256 * i;
      const int r = cc >> 4, c0 = (cc & 15) * 8;
      const int seq = b * S + j * BLK + c * 64 + r;
      *(u16x8*)&cb[r][c0] = *(const u16x8*)&qkv[(size_t)seq * NQKV + h * 384 + 128 + c0];
    }
    __syncthreads();
    float a2[4][8] = {};                   // qk: 4 m-rows x 8 m'-cols
    for (int eo = 0; eo < 16; ++eo) {
      u16x8 qr[4], kr[8];
      #pragma unroll
      for (int i = 0; i < 4; ++i) qr[i] = *(const u16x8*)&ql[tq * 4 + i][eo * 8];
      #pragma unroll
      for (int jj = 0; jj < 8; ++jj) kr[jj] = *(const u16x8*)&cb[tp * 8 + jj][eo * 8];
      #pragma unroll
      for (int ee = 0; ee < 8; ++ee) {
        float kf[8];
        #pragma unroll
        for (int jj = 0; jj < 8; ++jj) kf[jj] = bf2f(kr[jj][ee]);
        #pragma unroll
        for (int i = 0; i < 4; ++i) {
          const float qv = bf2f(qr[i][ee]);
          #pragma unroll
          for (int jj = 0; jj < 8; ++jj) a2[i][jj] += qv * kf[jj];
        }
      }
    }
    #pragma unroll
    for (int i = 0; i < 4; ++i) {          // decay + causal mask, write P
      const int gm = half * 128 + tq * 4 + i;
      u16x8 pw;
      #pragma unroll
      for (int jj = 0; jj < 8; ++jj) {
        const int gp = c * 64 + tp * 8 + jj;
        const float dd = (gm >= gp) ? expf(-slope * (float)(gm - gp)) : 0.f;
        pw[jj] = f2bf(a2[i][jj] * dd);
      }
      *(u16x8*)&pl[tq * 4 + i][tp * 8] = pw;
    }
    __syncthreads();
    #pragma unroll
    for (int i = 0; i < 4; ++i) {          // stage v chunk (reuse cb)
      const int cc = t + 256 * i;
      const int r = cc >> 4, c0 = (cc & 15) * 8;
      const int seq = b * S + j * BLK + c * 64 + r;
      *(u16x8*)&cb[r][c0] = *(const u16x8*)&qkv[(size_t)seq * NQKV + h * 384 + 256 + c0];
    }
    __syncthreads();
    for (int mo = 0; mo < 8; ++mo) {       // diag accumulate: P @ v
      u16x8 pr[8];
      #pragma unroll
      for (int i = 0; i < 8; ++i) pr[i] = *(const u16x8*)&pl[m0 + i][mo * 8];
      #pragma unroll
      for (int mm = 0; mm < 8; ++mm) {
        const u16x8 vv = *(const u16x8*)&cb[mo * 8 + mm][f0];
        float vf[8];
        #pragma unroll
        for (int q2 = 0; q2 < 8; ++q2) vf[q2] = bf2f(vv[q2]);
        #pragma unroll
        for (int i = 0; i < 8; ++i) {
          const float pv = bf2f(pr[i][mm]);
          #pragma unroll
          for (int q2 = 0; q2 < 8; ++q2) acc[i][q2] += pv * vf[q2];
        }
      }
    }
  }
  #pragma unroll
  for (int i = 0; i < 8; ++i) {            // write o[b][n][h*D + f]
    const int seq = b * S + j * BLK + half * 128 + m0 + i;
    u16x8 ow;
    #pragma unroll
    for (int q2 = 0; q2 < 8; ++q2) ow[q2] = f2bf(acc[i][q2]);
    *(u16x8*)&ob[(size_t)seq * HD + h * D + f0] = ow;
  }
}

// ---------------- RMSNorm * norm_w * sigmoid-gate -> bf16 ------------------
__global__ __launch_bounds__(256) void norm_gate(
    const unsigned short* __restrict__ ob, const unsigned short* __restrict__ gb,
    const float* __restrict__ nw, unsigned short* __restrict__ og) {
  const int row = blockIdx.x;
  const int t = threadIdx.x;
  const u16x8 ov = *(const u16x8*)&ob[(size_t)row * HD + t * 8];
  float f[8];
  float ss = 0.f;
  #pragma unroll
  for (int i = 0; i < 8; ++i) { f[i] = bf2f(ov[i]); ss += f[i] * f[i]; }
  #pragma unroll
  for (int off = 32; off > 0; off >>= 1) ss += __shfl_down(ss, off, 64);
  __shared__ float red[4];
  if ((t & 63) == 0) red[t >> 6] = ss;
  __syncthreads();
  const float rms = rsqrtf((red[0] + red[1] + red[2] + red[3]) * (1.f / HD) + 1e-6f);
  const u16x8 gv = *(const u16x8*)&gb[(size_t)row * HD + t * 8];
  u16x8 ow;
  #pragma unroll
  for (int i = 0; i < 8; ++i)
    ow[i] = f2bf(f[i] * rms * nw[t * 8 + i] * bf2f(gv[i]));
  *(u16x8*)&og[(size_t)row * HD + t * 8] = ow;
}

extern "C" void kernel_launch(void* const* d_in, const int* in_sizes, int n_in,
                              void* d_out, int out_size, void* d_ws, size_t ws_size,
                              hipStream_t stream) {
  (void)in_sizes; (void)n_in; (void)out_size; (void)ws_size;
  const float* x    = (const float*)d_in[0];
  const float* Wqkv = (const float*)d_in[1];
  const float* Wg   = (const float*)d_in[2];
  const float* Wout = (const float*)d_in[3];
  const float* nw   = (const float*)d_in[4];

  char* ws = (char*)d_ws;
  unsigned short* xb    = (unsigned short*)ws; ws += SZ_XB;
  unsigned short* wqkvt = (unsigned short*)ws; ws += SZ_WQKVT;
  unsigned short* wgt   = (unsigned short*)ws; ws += SZ_WGT;
  unsigned short* woutt = (unsigned short*)ws; ws += SZ_WOUTT;
  unsigned short* qkvb  = (unsigned short*)ws; ws += SZ_QKVB;
  unsigned short* gb    = (unsigned short*)ws; ws += SZ_GB;
  unsigned short* st    = (unsigned short*)ws; ws += SZ_ST;
  unsigned short* ob    = (unsigned short*)ws; ws += SZ_OB;
  unsigned short* og    = xb;  // alias: xb is dead after the gate GEMM

  // precision prep
  cvt_bf16<<<dim3((NB * S * DIN) / (256 * 8)), 256, 0, stream>>>(x, xb);
  transpose_cvt<<<dim3(NQKV / 32, DIN / 32), 256, 0, stream>>>(Wqkv, wqkvt, DIN, NQKV);
  transpose_cvt<<<dim3(HD / 32, DIN / 32), 256, 0, stream>>>(Wg, wgt, DIN, HD);
  transpose_cvt<<<dim3(HD / 32, HD / 32), 256, 0, stream>>>(Wout, woutt, HD, HD);

  // qkv = silu(x @ Wqkv), gate = sigmoid(x @ Wg)
  gemm_bt<1><<<dim3(NQKV / 128, (NB * S) / 128), 256, 0, stream>>>(xb, wqkvt, qkvb, NB * S, NQKV, DIN);
  gemm_bt<2><<<dim3(HD / 128, (NB * S) / 128), 256, 0, stream>>>(xb, wgt, gb, NB * S, HD, DIN);

  // blocked linear attention
  kv_outer<<<dim3(NB * H * NBL), 256, 0, stream>>>(qkvb, st);
  kv_scan<<<dim3((NB * H * D * D) / 256), 256, 0, stream>>>(st);
  attn_main<<<dim3(NB * H * NBL * 2), 256, 0, stream>>>(qkvb, st, ob);

  // norm + gate, final projection into d_out (fp32)
  norm_gate<<<dim3(NB * S), 256, 0, stream>>>(ob, gb, nw, og);
  gemm_bt<0><<<dim3(HD / 128, (NB * S) / 128), 256, 0, stream>>>(og, woutt, d_out, NB * S, HD, HD);
}

// Round 2
// 612.655 us; speedup vs baseline: 1.6289x; 1.6289x over previous
//
#include <hip/hip_runtime.h>
#include <cstddef>

typedef float f32x4 __attribute__((ext_vector_type(4)));
typedef __bf16 bf16x8 __attribute__((ext_vector_type(8)));
typedef unsigned short u16x8 __attribute__((ext_vector_type(8)));
typedef unsigned short u16x4 __attribute__((ext_vector_type(4)));

constexpr int NB = 2, S = 4096, H = 16, D = 128;
constexpr int DIN = 2048, NQKV = 6144, HD = 2048;
constexpr int BLK = 256, NBL = 16;

constexpr size_t SZ_XB    = (size_t)NB * S * DIN * 2;
constexpr size_t SZ_WQKVT = (size_t)NQKV * DIN * 2;
constexpr size_t SZ_WGT   = (size_t)HD * DIN * 2;
constexpr size_t SZ_WOUTT = (size_t)HD * HD * 2;
constexpr size_t SZ_QKVB  = (size_t)NB * S * NQKV * 2;
constexpr size_t SZ_GB    = (size_t)NB * S * HD * 2;
constexpr size_t SZ_ST    = (size_t)NB * H * NBL * D * D * 2;
constexpr size_t SZ_OB    = (size_t)NB * S * HD * 2;

__device__ __forceinline__ float bf2f(unsigned short u) {
  return __uint_as_float(((unsigned)u) << 16);
}
__device__ __forceinline__ unsigned short f2bf(float f) {
  unsigned u = __float_as_uint(f);
  u += 0x7fffu + ((u >> 16) & 1u);
  return (unsigned short)(u >> 16);
}
__device__ __forceinline__ void gload16(const unsigned short* g, unsigned short* l) {
  __builtin_amdgcn_global_load_lds(
      (const __attribute__((address_space(1))) unsigned int*)g,
      (__attribute__((address_space(3))) unsigned int*)l, 16, 0, 0);
}

// ---------------- fp32 -> bf16 elementwise convert (8 elems/thread) --------
__global__ __launch_bounds__(256) void cvt_bf16(
    const float* __restrict__ in, unsigned short* __restrict__ out) {
  const size_t id = (size_t)blockIdx.x * 256 + threadIdx.x;
  const float4 a = *(const float4*)&in[id * 8];
  const float4 c = *(const float4*)&in[id * 8 + 4];
  u16x8 o;
  o[0] = f2bf(a.x); o[1] = f2bf(a.y); o[2] = f2bf(a.z); o[3] = f2bf(a.w);
  o[4] = f2bf(c.x); o[5] = f2bf(c.y); o[6] = f2bf(c.z); o[7] = f2bf(c.w);
  *(u16x8*)&out[id * 8] = o;
}

// ---------------- W[K][N] f32  ->  Wt[N][K] bf16 (32x32 LDS tiles) ---------
__global__ __launch_bounds__(256) void transpose_cvt(
    const float* __restrict__ W, unsigned short* __restrict__ Wt, int K, int N) {
  __shared__ unsigned short tile[32][33];
  const int n0 = blockIdx.x * 32, k0 = blockIdx.y * 32;
  const int t = threadIdx.x;
  const int r = t >> 3, c4 = (t & 7) * 4;
  const float4 v = *(const float4*)&W[(size_t)(k0 + r) * N + n0 + c4];
  tile[r][c4 + 0] = f2bf(v.x);
  tile[r][c4 + 1] = f2bf(v.y);
  tile[r][c4 + 2] = f2bf(v.z);
  tile[r][c4 + 3] = f2bf(v.w);
  __syncthreads();
  u16x4 o;
  #pragma unroll
  for (int i = 0; i < 4; ++i) o[i] = tile[c4 + i][r];
  *(u16x4*)&Wt[(size_t)(n0 + r) * K + k0 + c4] = o;
}

// ---------------- bf16 MFMA GEMM (m97 structure): C = act(A @ Bt^T) --------
// A [M][K], Bt [N][K] bf16 row-major. 128x128 tile, BK=64, linear LDS +
// global_load_lds width 16. ACT: 0 none->f32, 1 silu->bf16, 2 sigmoid->bf16.
template<int ACT>
__global__ __launch_bounds__(256) void gemm_bt(
    const unsigned short* __restrict__ A, const unsigned short* __restrict__ Bt,
    void* __restrict__ C, int M, int N, int K) {
  __shared__ unsigned short Al[128 * 64];
  __shared__ unsigned short Bl[128 * 64];
  const int t = threadIdx.x;
  const int bn = blockIdx.x, bm = blockIdx.y;
  const int lane = t & 63, wave = t >> 6, wr = wave >> 1, wc = wave & 1;
  f32x4 acc[4][4] = {};
  const int lrow = t >> 3, lcol = (t & 7) * 8;
  const size_t arow = (size_t)(bm * 128 + lrow) * K + lcol;
  const size_t brow = (size_t)(bn * 128 + lrow) * K + lcol;
  for (int k0 = 0; k0 < K; k0 += 64) {
    if (k0) __syncthreads();
    #pragma unroll
    for (int p = 0; p < 4; ++p) {
      gload16(&A[arow + (size_t)p * 32 * K + k0], &Al[wave * 512 + p * 2048]);
      gload16(&Bt[brow + (size_t)p * 32 * K + k0], &Bl[wave * 512 + p * 2048]);
    }
    __syncthreads();
    #pragma unroll
    for (int kk = 0; kk < 2; ++kk) {
      bf16x8 af[4], bfr[4];
      #pragma unroll
      for (int m = 0; m < 4; ++m)
        af[m] = *(const bf16x8*)&Al[(wr * 64 + m * 16 + (lane & 15)) * 64 + kk * 32 + (lane >> 4) * 8];
      #pragma unroll
      for (int n = 0; n < 4; ++n)
        bfr[n] = *(const bf16x8*)&Bl[(wc * 64 + n * 16 + (lane & 15)) * 64 + kk * 32 + (lane >> 4) * 8];
      #pragma unroll
      for (int m = 0; m < 4; ++m)
        #pragma unroll
        for (int n = 0; n < 4; ++n)
          acc[m][n] = __builtin_amdgcn_mfma_f32_16x16x32_bf16(af[m], bfr[n], acc[m][n], 0, 0, 0);
    }
  }
  // epilogue: C/D layout col = lane&15, row = (lane>>4)*4 + reg  [m89-verified]
  const int ro = (lane >> 4) * 4, co = lane & 15;
  #pragma unroll
  for (int m = 0; m < 4; ++m)
    #pragma unroll
    for (int n = 0; n < 4; ++n) {
      const int gc = bn * 128 + wc * 64 + n * 16 + co;
      #pragma unroll
      for (int r = 0; r < 4; ++r) {
        const int gr = bm * 128 + wr * 64 + m * 16 + ro + r;
        float v = acc[m][n][r];
        if constexpr (ACT == 1) v = v / (1.f + __expf(-v));     // silu
        if constexpr (ACT == 2) v = 1.f / (1.f + __expf(-v));   // sigmoid
        if constexpr (ACT == 0) ((float*)C)[(size_t)gr * N + gc] = v;
        else ((unsigned short*)C)[(size_t)gr * N + gc] = f2bf(v);
      }
    }
}

// ---------------- per-block KV outer product, TRANSPOSED out ---------------
// st[(bh*NBL+j)][f][e] = sum_m (k[m][e]*kdecay[m]) * v[m][f]   (bf16)
__global__ __launch_bounds__(256) void kv_outer(
    const unsigned short* __restrict__ qkv, unsigned short* __restrict__ st) {
  const int gid = blockIdx.x;
  const int j = gid & 15;
  const int bh = gid >> 4;
  const int h = bh & 15;
  const int b = bh >> 4;
  const float slope = exp2f(-0.5f * (float)(h + 1));
  const int t = threadIdx.x;
  __shared__ unsigned short kl[64][136];
  __shared__ unsigned short vl[64][136];
  float acc[8][8] = {};
  const int e0 = (t >> 4) * 8, f0 = (t & 15) * 8;
  for (int ch = 0; ch < 4; ++ch) {
    if (ch) __syncthreads();
    #pragma unroll
    for (int i = 0; i < 4; ++i) {
      const int cc = t + 256 * i;
      const int r = cc >> 4, c0 = (cc & 15) * 8;
      const int mb = ch * 64 + r;
      const int seq = b * S + j * BLK + mb;
      const u16x8 k8 = *(const u16x8*)&qkv[(size_t)seq * NQKV + h * 384 + 128 + c0];
      const float kd = expf(-slope * (float)(255 - mb));
      u16x8 kw;
      #pragma unroll
      for (int q2 = 0; q2 < 8; ++q2) kw[q2] = f2bf(bf2f(k8[q2]) * kd);
      *(u16x8*)&kl[r][c0] = kw;
      *(u16x8*)&vl[r][c0] = *(const u16x8*)&qkv[(size_t)seq * NQKV + h * 384 + 256 + c0];
    }
    __syncthreads();
    for (int m = 0; m < 64; ++m) {
      const u16x8 k8 = *(const u16x8*)&kl[m][e0];
      const u16x8 v8 = *(const u16x8*)&vl[m][f0];
      float kf[8], vf[8];
      #pragma unroll
      for (int q2 = 0; q2 < 8; ++q2) { kf[q2] = bf2f(k8[q2]); vf[q2] = bf2f(v8[q2]); }
      #pragma unroll
      for (int i = 0; i < 8; ++i)
        #pragma unroll
        for (int q2 = 0; q2 < 8; ++q2) acc[i][q2] += kf[i] * vf[q2];
    }
  }
  const size_t base = (size_t)gid * (D * D);
  #pragma unroll
  for (int q2 = 0; q2 < 8; ++q2) {           // transposed: st[f][e]
    u16x8 ow;
    #pragma unroll
    for (int i = 0; i < 8; ++i) ow[i] = f2bf(acc[i][q2]);
    *(u16x8*)&st[base + (size_t)(f0 + q2) * D + e0] = ow;
  }
}

// ---------------- exclusive decay scan over blocks (per element) -----------
__global__ __launch_bounds__(256) void kv_scan(unsigned short* __restrict__ st) {
  const int id = blockIdx.x * 256 + threadIdx.x;  // NB*H*D*D threads
  const int ef = id & (D * D - 1);
  const int bh = id >> 14;
  const int h = bh & 15;
  const float slope = exp2f(-0.5f * (float)(h + 1));
  const float bd = expf(-slope * 256.f);
  unsigned short* p = st + (size_t)bh * NBL * D * D + ef;
  float cur = 0.f;
  #pragma unroll
  for (int jj = 0; jj < NBL; ++jj) {
    const float m = bf2f(p[(size_t)jj * D * D]);
    p[(size_t)jj * D * D] = f2bf(cur);
    cur = bd * cur + m;
  }
}

// ---------------- MFMA attention -------------------------------------------
// grid = ((b*H+h)*NBL + j)*2 + half ; WG = 4 waves, 128 q-rows x 128 dims.
// out = qdecay.*(q @ kvT^T) + (mask(q@k^T).*decay) @ v
__global__ __launch_bounds__(256) void attn_mfma(
    const unsigned short* __restrict__ qkv, const unsigned short* __restrict__ st,
    unsigned short* __restrict__ ob) {
  const int gid = blockIdx.x;
  const int half = gid & 1;
  const int rest = gid >> 1;
  const int j = rest & 15;
  const int bh = rest >> 4;
  const int h = bh & 15;
  const int b = bh >> 4;
  const float slope = exp2f(-0.5f * (float)(h + 1));
  const int t = threadIdx.x;
  const int lane = t & 63, wave = t >> 6, wr = wave >> 1, wc = wave & 1;

  __shared__ unsigned short ql[128][136];   // q rows (m x e)
  __shared__ unsigned short cb[128][136];   // kvT / k / vT chunk buffer
  __shared__ unsigned short pl[128][136];   // decayed P (m x m') bf16

  // stage q and kvT (state is pre-transposed [f][e], exclusive-scanned)
  {
    const int r = t >> 4, c0 = (t & 15) * 8;
    const size_t stbase = (size_t)rest * (D * D);
    #pragma unroll
    for (int p = 0; p < 8; ++p) {
      const int seq = b * S + j * BLK + half * 128 + r + p * 16;
      *(u16x8*)&ql[r + p * 16][c0] = *(const u16x8*)&qkv[(size_t)seq * NQKV + h * 384 + c0];
      *(u16x8*)&cb[r + p * 16][c0] = *(const u16x8*)&st[stbase + (size_t)(r + p * 16) * D + c0];
    }
  }
  __syncthreads();

  f32x4 acc[4][4] = {};
  // ---- phase 1: non-diag = q @ kvT^T ----
  #pragma unroll
  for (int kk = 0; kk < 4; ++kk) {
    bf16x8 af[4], bfr[4];
    #pragma unroll
    for (int m = 0; m < 4; ++m)
      af[m] = *(const bf16x8*)&ql[wr * 64 + m * 16 + (lane & 15)][kk * 32 + (lane >> 4) * 8];
    #pragma unroll
    for (int n = 0; n < 4; ++n)
      bfr[n] = *(const bf16x8*)&cb[wc * 64 + n * 16 + (lane & 15)][kk * 32 + (lane >> 4) * 8];
    #pragma unroll
    for (int m = 0; m < 4; ++m)
      #pragma unroll
      for (int n = 0; n < 4; ++n)
        acc[m][n] = __builtin_amdgcn_mfma_f32_16x16x32_bf16(af[m], bfr[n], acc[m][n], 0, 0, 0);
  }
  // apply q_decay = exp(-slope*(gm+1)) to the non-diag part
  const int ro = (lane >> 4) * 4;
  #pragma unroll
  for (int m = 0; m < 4; ++m)
    #pragma unroll
    for (int r = 0; r < 4; ++r) {
      const int gm = half * 128 + wr * 64 + m * 16 + ro + r;
      const float qd = expf(-slope * (float)(gm + 1));
      #pragma unroll
      for (int n = 0; n < 4; ++n) acc[m][n][r] *= qd;
    }

  // ---- phase 2: intra-block causal, chunks of 128 k-rows ----
  const int nch = 1 + half;
  for (int c = 0; c < nch; ++c) {
    __syncthreads();                         // cb free (prev readers done)
    {
      const int r = t >> 4, c0 = (t & 15) * 8;
      #pragma unroll
      for (int p = 0; p < 8; ++p) {
        const int seq = b * S + j * BLK + c * 128 + r + p * 16;
        *(u16x8*)&cb[r + p * 16][c0] = *(const u16x8*)&qkv[(size_t)seq * NQKV + h * 384 + 128 + c0];
      }
    }
    __syncthreads();
    f32x4 sacc[4][4] = {};
    #pragma unroll
    for (int kk = 0; kk < 4; ++kk) {
      bf16x8 af[4], bfr[4];
      #pragma unroll
      for (int m = 0; m < 4; ++m)
        af[m] = *(const bf16x8*)&ql[wr * 64 + m * 16 + (lane & 15)][kk * 32 + (lane >> 4) * 8];
      #pragma unroll
      for (int n = 0; n < 4; ++n)
        bfr[n] = *(const bf16x8*)&cb[wc * 64 + n * 16 + (lane & 15)][kk * 32 + (lane >> 4) * 8];
      #pragma unroll
      for (int m = 0; m < 4; ++m)
        #pragma unroll
        for (int n = 0; n < 4; ++n)
          sacc[m][n] = __builtin_amdgcn_mfma_f32_16x16x32_bf16(af[m], bfr[n], sacc[m][n], 0, 0, 0);
    }
    // decay+mask -> P (bf16) in LDS
    #pragma unroll
    for (int m = 0; m < 4; ++m)
      #pragma unroll
      for (int n = 0; n < 4; ++n) {
        const int lc = wc * 64 + n * 16 + (lane & 15);
        const int gp = c * 128 + lc;
        #pragma unroll
        for (int r = 0; r < 4; ++r) {
          const int lm = wr * 64 + m * 16 + ro + r;
          const int gm = half * 128 + lm;
          const float dd = (gm >= gp) ? expf(-slope * (float)(gm - gp)) : 0.f;
          pl[lm][lc] = f2bf(sacc[m][n][r] * dd);
        }
      }
    __syncthreads();                         // P complete; cb readers done
    // stage v transposed: cb[f][m']
    {
      const int vr = t & 15, vc0 = (t >> 4) * 8;
      #pragma unroll
      for (int p = 0; p < 8; ++p) {
        const int row = vr + p * 16;
        const int seq = b * S + j * BLK + c * 128 + row;
        const u16x8 vv = *(const u16x8*)&qkv[(size_t)seq * NQKV + h * 384 + 256 + vc0];
        #pragma unroll
        for (int i = 0; i < 8; ++i) cb[vc0 + i][row] = vv[i];
      }
    }
    __syncthreads();
    // PV: acc += P @ vT^T
    #pragma unroll
    for (int kk = 0; kk < 4; ++kk) {
      bf16x8 af[4], bfr[4];
      #pragma unroll
      for (int m = 0; m < 4; ++m)
        af[m] = *(const bf16x8*)&pl[wr * 64 + m * 16 + (lane & 15)][kk * 32 + (lane >> 4) * 8];
      #pragma unroll
      for (int n = 0; n < 4; ++n)
        bfr[n] = *(const bf16x8*)&cb[wc * 64 + n * 16 + (lane & 15)][kk * 32 + (lane >> 4) * 8];
      #pragma unroll
      for (int m = 0; m < 4; ++m)
        #pragma unroll
        for (int n = 0; n < 4; ++n)
          acc[m][n] = __builtin_amdgcn_mfma_f32_16x16x32_bf16(af[m], bfr[n], acc[m][n], 0, 0, 0);
    }
  }

  // epilogue: ob[b][n][h*D + f]
  #pragma unroll
  for (int m = 0; m < 4; ++m)
    #pragma unroll
    for (int n = 0; n < 4; ++n) {
      const int fc = h * D + wc * 64 + n * 16 + (lane & 15);
      #pragma unroll
      for (int r = 0; r < 4; ++r) {
        const int seq = b * S + j * BLK + half * 128 + wr * 64 + m * 16 + ro + r;
        ob[(size_t)seq * HD + fc] = f2bf(acc[m][n][r]);
      }
    }
}

// ---------------- RMSNorm * norm_w * sigmoid-gate -> bf16 ------------------
__global__ __launch_bounds__(256) void norm_gate(
    const unsigned short* __restrict__ ob, const unsigned short* __restrict__ gb,
    const float* __restrict__ nw, unsigned short* __restrict__ og) {
  const int row = blockIdx.x;
  const int t = threadIdx.x;
  const u16x8 ov = *(const u16x8*)&ob[(size_t)row * HD + t * 8];
  float f[8];
  float ss = 0.f;
  #pragma unroll
  for (int i = 0; i < 8; ++i) { f[i] = bf2f(ov[i]); ss += f[i] * f[i]; }
  #pragma unroll
  for (int off = 32; off > 0; off >>= 1) ss += __shfl_down(ss, off, 64);
  __shared__ float red[4];
  if ((t & 63) == 0) red[t >> 6] = ss;
  __syncthreads();
  const float rms = rsqrtf((red[0] + red[1] + red[2] + red[3]) * (1.f / HD) + 1e-6f);
  const u16x8 gv = *(const u16x8*)&gb[(size_t)row * HD + t * 8];
  u16x8 ow;
  #pragma unroll
  for (int i = 0; i < 8; ++i)
    ow[i] = f2bf(f[i] * rms * nw[t * 8 + i] * bf2f(gv[i]));
  *(u16x8*)&og[(size_t)row * HD + t * 8] = ow;
}

extern "C" void kernel_launch(void* const* d_in, const int* in_sizes, int n_in,
                              void* d_out, int out_size, void* d_ws, size_t ws_size,
                              hipStream_t stream) {
  (void)in_sizes; (void)n_in; (void)out_size; (void)ws_size;
  const float* x    = (const float*)d_in[0];
  const float* Wqkv = (const float*)d_in[1];
  const float* Wg   = (const float*)d_in[2];
  const float* Wout = (const float*)d_in[3];
  const float* nw   = (const float*)d_in[4];

  char* ws = (char*)d_ws;
  unsigned short* xb    = (unsigned short*)ws; ws += SZ_XB;
  unsigned short* wqkvt = (unsigned short*)ws; ws += SZ_WQKVT;
  unsigned short* wgt   = (unsigned short*)ws; ws += SZ_WGT;
  unsigned short* woutt = (unsigned short*)ws; ws += SZ_WOUTT;
  unsigned short* qkvb  = (unsigned short*)ws; ws += SZ_QKVB;
  unsigned short* gb    = (unsigned short*)ws; ws += SZ_GB;
  unsigned short* st    = (unsigned short*)ws; ws += SZ_ST;
  unsigned short* ob    = (unsigned short*)ws; ws += SZ_OB;
  unsigned short* og    = xb;  // alias: xb dead after the gate GEMM

  cvt_bf16<<<dim3((NB * S * DIN) / (256 * 8)), 256, 0, stream>>>(x, xb);
  transpose_cvt<<<dim3(NQKV / 32, DIN / 32), 256, 0, stream>>>(Wqkv, wqkvt, DIN, NQKV);
  transpose_cvt<<<dim3(HD / 32, DIN / 32), 256, 0, stream>>>(Wg, wgt, DIN, HD);
  transpose_cvt<<<dim3(HD / 32, HD / 32), 256, 0, stream>>>(Wout, woutt, HD, HD);

  gemm_bt<1><<<dim3(NQKV / 128, (NB * S) / 128), 256, 0, stream>>>(xb, wqkvt, qkvb, NB * S, NQKV, DIN);
  gemm_bt<2><<<dim3(HD / 128, (NB * S) / 128), 256, 0, stream>>>(xb, wgt, gb, NB * S, HD, DIN);

  kv_outer<<<dim3(NB * H * NBL), 256, 0, stream>>>(qkvb, st);
  kv_scan<<<dim3((NB * H * D * D) / 256), 256, 0, stream>>>(st);
  attn_mfma<<<dim3(NB * H * NBL * 2), 256, 0, stream>>>(qkvb, st, ob);

  norm_gate<<<dim3(NB * S), 256, 0, stream>>>(ob, gb, nw, og);
  gemm_bt<0><<<dim3(HD / 128, (NB * S) / 128), 256, 0, stream>>>(og, woutt, d_out, NB * S, HD, HD);
}

// Round 3
// 532.376 us; speedup vs baseline: 1.8746x; 1.1508x over previous
//
#include <hip/hip_runtime.h>
#include <cstddef>

typedef float f32x4 __attribute__((ext_vector_type(4)));
typedef __bf16 bf16x8 __attribute__((ext_vector_type(8)));
typedef unsigned short u16x8 __attribute__((ext_vector_type(8)));
typedef unsigned short u16x4 __attribute__((ext_vector_type(4)));

constexpr int NB = 2, S = 4096, H = 16, D = 128;
constexpr int DIN = 2048, NQKV = 6144, HD = 2048;
constexpr int BLK = 256, NBL = 16;

constexpr size_t SZ_XB    = (size_t)NB * S * DIN * 2;
constexpr size_t SZ_WQKVT = (size_t)NQKV * DIN * 2;
constexpr size_t SZ_WGT   = (size_t)HD * DIN * 2;
constexpr size_t SZ_WOUTT = (size_t)HD * HD * 2;
constexpr size_t SZ_QKVB  = (size_t)NB * S * NQKV * 2;
constexpr size_t SZ_GB    = (size_t)NB * S * HD * 2;
constexpr size_t SZ_ST    = (size_t)NB * H * NBL * D * D * 2;
constexpr size_t SZ_OB    = (size_t)NB * S * HD * 2;

__device__ __forceinline__ float bf2f(unsigned short u) {
  return __uint_as_float(((unsigned)u) << 16);
}
__device__ __forceinline__ unsigned short f2bf(float f) {
  unsigned u = __float_as_uint(f);
  u += 0x7fffu + ((u >> 16) & 1u);
  return (unsigned short)(u >> 16);
}
__device__ __forceinline__ void gload16(const void* g, void* l) {
  __builtin_amdgcn_global_load_lds(
      (const __attribute__((address_space(1))) unsigned int*)g,
      (__attribute__((address_space(3))) unsigned int*)l, 16, 0, 0);
}

// ---------------- fp32 -> bf16 elementwise convert (8 elems/thread) --------
__global__ __launch_bounds__(256) void cvt_bf16(
    const float* __restrict__ in, unsigned short* __restrict__ out) {
  const size_t id = (size_t)blockIdx.x * 256 + threadIdx.x;
  const float4 a = *(const float4*)&in[id * 8];
  const float4 c = *(const float4*)&in[id * 8 + 4];
  u16x8 o;
  o[0] = f2bf(a.x); o[1] = f2bf(a.y); o[2] = f2bf(a.z); o[3] = f2bf(a.w);
  o[4] = f2bf(c.x); o[5] = f2bf(c.y); o[6] = f2bf(c.z); o[7] = f2bf(c.w);
  *(u16x8*)&out[id * 8] = o;
}

// ---------------- W[K][N] f32  ->  Wt[N][K] bf16 (32x32 LDS tiles) ---------
__global__ __launch_bounds__(256) void transpose_cvt(
    const float* __restrict__ W, unsigned short* __restrict__ Wt, int K, int N) {
  __shared__ unsigned short tile[32][33];
  const int n0 = blockIdx.x * 32, k0 = blockIdx.y * 32;
  const int t = threadIdx.x;
  const int r = t >> 3, c4 = (t & 7) * 4;
  const float4 v = *(const float4*)&W[(size_t)(k0 + r) * N + n0 + c4];
  tile[r][c4 + 0] = f2bf(v.x);
  tile[r][c4 + 1] = f2bf(v.y);
  tile[r][c4 + 2] = f2bf(v.z);
  tile[r][c4 + 3] = f2bf(v.w);
  __syncthreads();
  u16x4 o;
  #pragma unroll
  for (int i = 0; i < 4; ++i) o[i] = tile[c4 + i][r];
  *(u16x4*)&Wt[(size_t)(n0 + r) * K + k0 + c4] = o;
}

// ---------------- 256^2 deep-pipeline bf16 MFMA GEMM: C = act(A @ Bt^T) ----
// A [M][K], Bt [N][K] bf16 row-major. 512 thr = 8 waves (2Mx4N), 128x64/wave.
// K split into 32-wide units; 4-slot LDS ring (A 16K + B 16K per slot);
// staging 3 units ahead via global_load_lds; counted vmcnt; one barrier/unit.
// LDS swizzle: byte(r,c) = (r>>4)*1024 + (((r&15)*64 + 2c) ^ ((r&6)<<3)).
// Staging keeps LDS linear; the global SOURCE is pre-swizzled (involution).
// ACT: 0 none->f32, 1 silu->bf16, 2 sigmoid->bf16.
template<int ACT>
__global__ __launch_bounds__(512, 2) void gemm256(
    const unsigned short* __restrict__ A, const unsigned short* __restrict__ Bt,
    void* __restrict__ C, int M, int N, int K) {
  __shared__ unsigned short lds[65536];          // 128 KiB = 4 slots x 32 KiB
  char* ldsb = (char*)lds;
  const int t = threadIdx.x;
  const int lane = t & 63, wave = t >> 6;
  const int wr = wave >> 2, wc = wave & 3;       // 2 x 4 wave grid

  // XCD-aware bijective block swizzle (grid % 8 == 0 for all our shapes)
  const int nbn = N >> 8;
  const int nwg = gridDim.x;
  int lin = blockIdx.x;
  lin = (lin & 7) * (nwg >> 3) + (lin >> 3);
  const int bm = lin / nbn, bn = lin % nbn;

  // ---- staging address precompute (swizzle-decoded global source) ----
  const int subr = lane >> 2;                    // 0..15 row within 16-row grp
  const int sw = (subr & 6) << 3;                // XOR bits 4,5
  const int cstg = ((((lane & 3) << 4) ^ sw) >> 1);   // col elem 0/8/16/24
  const int r0 = wave * 32 + subr;               // issue-0 row (0..255)
  const unsigned short* srcA0 = A  + (size_t)(bm * 256 + r0) * K + cstg;
  const unsigned short* srcA1 = A  + (size_t)(bm * 256 + r0 + 16) * K + cstg;
  const unsigned short* srcB0 = Bt + (size_t)(bn * 256 + r0) * K + cstg;
  const unsigned short* srcB1 = Bt + (size_t)(bn * 256 + r0 + 16) * K + cstg;
  const int dst0 = wave * 2048, dst1 = dst0 + 1024;   // bytes within region

  // ---- ds_read fragment offsets (swizzled) ----
  const int colb = (lane >> 4) << 4;             // 0/16/32/48 bytes
  int offA[8], offB[4];
  #pragma unroll
  for (int m = 0; m < 8; ++m) {
    const int row = wr * 128 + m * 16 + (lane & 15);
    offA[m] = ((row >> 4) << 10) + (((((row & 15) << 6) | colb)) ^ ((row & 6) << 3));
  }
  #pragma unroll
  for (int n = 0; n < 4; ++n) {
    const int row = wc * 64 + n * 16 + (lane & 15);
    offB[n] = ((row >> 4) << 10) + (((((row & 15) << 6) | colb)) ^ ((row & 6) << 3));
  }

  const int NU = K >> 5;                         // 32-wide K units (K=2048 -> 64)
  #define STAGE(u) {                                                   \
    const int _s = ((u) & 3) * 32768;                                  \
    const int _ko = (u) * 32;                                          \
    gload16(srcA0 + _ko, ldsb + _s + dst0);                            \
    gload16(srcA1 + _ko, ldsb + _s + dst1);                            \
    gload16(srcB0 + _ko, ldsb + _s + 16384 + dst0);                    \
    gload16(srcB1 + _ko, ldsb + _s + 16384 + dst1);                    \
  }

  STAGE(0); STAGE(1); STAGE(2);

  f32x4 acc[8][4] = {};
  for (int u = 0; u < NU; ++u) {
    // wait for unit u's 4 loads (oldest); keep up to 2 future units in flight
    if (u < NU - 2)      asm volatile("s_waitcnt vmcnt(8)" ::: "memory");
    else if (u == NU - 2) asm volatile("s_waitcnt vmcnt(4)" ::: "memory");
    else                  asm volatile("s_waitcnt vmcnt(0)" ::: "memory");
    __builtin_amdgcn_s_barrier();                // unit u globally in LDS;
                                                 // unit u-1 readers all retired
    if (u + 3 < NU) STAGE(u + 3);                // overwrite slot(u-1): safe
    const int slot = (u & 3) * 32768;
    bf16x8 af[8], bf[4];
    #pragma unroll
    for (int m = 0; m < 8; ++m) af[m] = *(const bf16x8*)(ldsb + slot + offA[m]);
    #pragma unroll
    for (int n = 0; n < 4; ++n) bf[n] = *(const bf16x8*)(ldsb + slot + 16384 + offB[n]);
    __builtin_amdgcn_s_setprio(1);
    #pragma unroll
    for (int m = 0; m < 8; ++m)
      #pragma unroll
      for (int n = 0; n < 4; ++n)
        acc[m][n] = __builtin_amdgcn_mfma_f32_16x16x32_bf16(af[m], bf[n], acc[m][n], 0, 0, 0);
    __builtin_amdgcn_s_setprio(0);
  }
  #undef STAGE

  // epilogue: C/D layout col = lane&15, row = (lane>>4)*4 + reg  [m89-verified]
  const int ro = (lane >> 4) * 4, co = lane & 15;
  #pragma unroll
  for (int m = 0; m < 8; ++m)
    #pragma unroll
    for (int n = 0; n < 4; ++n) {
      const int gc = bn * 256 + wc * 64 + n * 16 + co;
      #pragma unroll
      for (int r = 0; r < 4; ++r) {
        const int gr = bm * 256 + wr * 128 + m * 16 + ro + r;
        float v = acc[m][n][r];
        if constexpr (ACT == 1) v = v / (1.f + __expf(-v));     // silu
        if constexpr (ACT == 2) v = 1.f / (1.f + __expf(-v));   // sigmoid
        if constexpr (ACT == 0) ((float*)C)[(size_t)gr * N + gc] = v;
        else ((unsigned short*)C)[(size_t)gr * N + gc] = f2bf(v);
      }
    }
}

// ---------------- per-block KV outer product, TRANSPOSED out ---------------
// st[(bh*NBL+j)][f][e] = sum_m (k[m][e]*kdecay[m]) * v[m][f]   (bf16)
__global__ __launch_bounds__(256) void kv_outer(
    const unsigned short* __restrict__ qkv, unsigned short* __restrict__ st) {
  const int gid = blockIdx.x;
  const int j = gid & 15;
  const int bh = gid >> 4;
  const int h = bh & 15;
  const int b = bh >> 4;
  const float slope = exp2f(-0.5f * (float)(h + 1));
  const int t = threadIdx.x;
  __shared__ unsigned short kl[64][136];
  __shared__ unsigned short vl[64][136];
  float acc[8][8] = {};
  const int e0 = (t >> 4) * 8, f0 = (t & 15) * 8;
  for (int ch = 0; ch < 4; ++ch) {
    if (ch) __syncthreads();
    #pragma unroll
    for (int i = 0; i < 4; ++i) {
      const int cc = t + 256 * i;
      const int r = cc >> 4, c0 = (cc & 15) * 8;
      const int mb = ch * 64 + r;
      const int seq = b * S + j * BLK + mb;
      const u16x8 k8 = *(const u16x8*)&qkv[(size_t)seq * NQKV + h * 384 + 128 + c0];
      const float kd = expf(-slope * (float)(255 - mb));
      u16x8 kw;
      #pragma unroll
      for (int q2 = 0; q2 < 8; ++q2) kw[q2] = f2bf(bf2f(k8[q2]) * kd);
      *(u16x8*)&kl[r][c0] = kw;
      *(u16x8*)&vl[r][c0] = *(const u16x8*)&qkv[(size_t)seq * NQKV + h * 384 + 256 + c0];
    }
    __syncthreads();
    for (int m = 0; m < 64; ++m) {
      const u16x8 k8 = *(const u16x8*)&kl[m][e0];
      const u16x8 v8 = *(const u16x8*)&vl[m][f0];
      float kf[8], vf[8];
      #pragma unroll
      for (int q2 = 0; q2 < 8; ++q2) { kf[q2] = bf2f(k8[q2]); vf[q2] = bf2f(v8[q2]); }
      #pragma unroll
      for (int i = 0; i < 8; ++i)
        #pragma unroll
        for (int q2 = 0; q2 < 8; ++q2) acc[i][q2] += kf[i] * vf[q2];
    }
  }
  const size_t base = (size_t)gid * (D * D);
  #pragma unroll
  for (int q2 = 0; q2 < 8; ++q2) {           // transposed: st[f][e]
    u16x8 ow;
    #pragma unroll
    for (int i = 0; i < 8; ++i) ow[i] = f2bf(acc[i][q2]);
    *(u16x8*)&st[base + (size_t)(f0 + q2) * D + e0] = ow;
  }
}

// ---------------- exclusive decay scan over blocks (per element) -----------
__global__ __launch_bounds__(256) void kv_scan(unsigned short* __restrict__ st) {
  const int id = blockIdx.x * 256 + threadIdx.x;  // NB*H*D*D threads
  const int ef = id & (D * D - 1);
  const int bh = id >> 14;
  const int h = bh & 15;
  const float slope = exp2f(-0.5f * (float)(h + 1));
  const float bd = expf(-slope * 256.f);
  unsigned short* p = st + (size_t)bh * NBL * D * D + ef;
  float cur = 0.f;
  #pragma unroll
  for (int jj = 0; jj < NBL; ++jj) {
    const float m = bf2f(p[(size_t)jj * D * D]);
    p[(size_t)jj * D * D] = f2bf(cur);
    cur = bd * cur + m;
  }
}

// ---------------- MFMA attention -------------------------------------------
// grid = ((b*H+h)*NBL + j)*2 + half ; WG = 4 waves, 128 q-rows x 128 dims.
// out = qdecay.*(q @ kvT^T) + (mask(q@k^T).*decay) @ v
__global__ __launch_bounds__(256) void attn_mfma(
    const unsigned short* __restrict__ qkv, const unsigned short* __restrict__ st,
    unsigned short* __restrict__ ob) {
  const int gid = blockIdx.x;
  const int half = gid & 1;
  const int rest = gid >> 1;
  const int j = rest & 15;
  const int bh = rest >> 4;
  const int h = bh & 15;
  const int b = bh >> 4;
  const float slope = exp2f(-0.5f * (float)(h + 1));
  const int t = threadIdx.x;
  const int lane = t & 63, wave = t >> 6, wr = wave >> 1, wc = wave & 1;

  __shared__ unsigned short ql[128][136];   // q rows (m x e)
  __shared__ unsigned short cb[128][136];   // kvT / k / vT chunk buffer
  __shared__ unsigned short pl[128][136];   // decayed P (m x m') bf16

  // stage q and kvT (state is pre-transposed [f][e], exclusive-scanned)
  {
    const int r = t >> 4, c0 = (t & 15) * 8;
    const size_t stbase = (size_t)rest * (D * D);
    #pragma unroll
    for (int p = 0; p < 8; ++p) {
      const int seq = b * S + j * BLK + half * 128 + r + p * 16;
      *(u16x8*)&ql[r + p * 16][c0] = *(const u16x8*)&qkv[(size_t)seq * NQKV + h * 384 + c0];
      *(u16x8*)&cb[r + p * 16][c0] = *(const u16x8*)&st[stbase + (size_t)(r + p * 16) * D + c0];
    }
  }
  __syncthreads();

  f32x4 acc[4][4] = {};
  // ---- phase 1: non-diag = q @ kvT^T ----
  #pragma unroll
  for (int kk = 0; kk < 4; ++kk) {
    bf16x8 af[4], bfr[4];
    #pragma unroll
    for (int m = 0; m < 4; ++m)
      af[m] = *(const bf16x8*)&ql[wr * 64 + m * 16 + (lane & 15)][kk * 32 + (lane >> 4) * 8];
    #pragma unroll
    for (int n = 0; n < 4; ++n)
      bfr[n] = *(const bf16x8*)&cb[wc * 64 + n * 16 + (lane & 15)][kk * 32 + (lane >> 4) * 8];
    #pragma unroll
    for (int m = 0; m < 4; ++m)
      #pragma unroll
      for (int n = 0; n < 4; ++n)
        acc[m][n] = __builtin_amdgcn_mfma_f32_16x16x32_bf16(af[m], bfr[n], acc[m][n], 0, 0, 0);
  }
  // apply q_decay = exp(-slope*(gm+1)) to the non-diag part
  const int ro = (lane >> 4) * 4;
  #pragma unroll
  for (int m = 0; m < 4; ++m)
    #pragma unroll
    for (int r = 0; r < 4; ++r) {
      const int gm = half * 128 + wr * 64 + m * 16 + ro + r;
      const float qd = expf(-slope * (float)(gm + 1));
      #pragma unroll
      for (int n = 0; n < 4; ++n) acc[m][n][r] *= qd;
    }

  // ---- phase 2: intra-block causal, chunks of 128 k-rows ----
  const int nch = 1 + half;
  for (int c = 0; c < nch; ++c) {
    __syncthreads();                         // cb free (prev readers done)
    {
      const int r = t >> 4, c0 = (t & 15) * 8;
      #pragma unroll
      for (int p = 0; p < 8; ++p) {
        const int seq = b * S + j * BLK + c * 128 + r + p * 16;
        *(u16x8*)&cb[r + p * 16][c0] = *(const u16x8*)&qkv[(size_t)seq * NQKV + h * 384 + 128 + c0];
      }
    }
    __syncthreads();
    f32x4 sacc[4][4] = {};
    #pragma unroll
    for (int kk = 0; kk < 4; ++kk) {
      bf16x8 af[4], bfr[4];
      #pragma unroll
      for (int m = 0; m < 4; ++m)
        af[m] = *(const bf16x8*)&ql[wr * 64 + m * 16 + (lane & 15)][kk * 32 + (lane >> 4) * 8];
      #pragma unroll
      for (int n = 0; n < 4; ++n)
        bfr[n] = *(const bf16x8*)&cb[wc * 64 + n * 16 + (lane & 15)][kk * 32 + (lane >> 4) * 8];
      #pragma unroll
      for (int m = 0; m < 4; ++m)
        #pragma unroll
        for (int n = 0; n < 4; ++n)
          sacc[m][n] = __builtin_amdgcn_mfma_f32_16x16x32_bf16(af[m], bfr[n], sacc[m][n], 0, 0, 0);
    }
    // decay+mask -> P (bf16) in LDS
    #pragma unroll
    for (int m = 0; m < 4; ++m)
      #pragma unroll
      for (int n = 0; n < 4; ++n) {
        const int lc = wc * 64 + n * 16 + (lane & 15);
        const int gp = c * 128 + lc;
        #pragma unroll
        for (int r = 0; r < 4; ++r) {
          const int lm = wr * 64 + m * 16 + ro + r;
          const int gm = half * 128 + lm;
          const float dd = (gm >= gp) ? expf(-slope * (float)(gm - gp)) : 0.f;
          pl[lm][lc] = f2bf(sacc[m][n][r] * dd);
        }
      }
    __syncthreads();                         // P complete; cb readers done
    // stage v transposed: cb[f][m']
    {
      const int vr = t & 15, vc0 = (t >> 4) * 8;
      #pragma unroll
      for (int p = 0; p < 8; ++p) {
        const int row = vr + p * 16;
        const int seq = b * S + j * BLK + c * 128 + row;
        const u16x8 vv = *(const u16x8*)&qkv[(size_t)seq * NQKV + h * 384 + 256 + vc0];
        #pragma unroll
        for (int i = 0; i < 8; ++i) cb[vc0 + i][row] = vv[i];
      }
    }
    __syncthreads();
    // PV: acc += P @ vT^T
    #pragma unroll
    for (int kk = 0; kk < 4; ++kk) {
      bf16x8 af[4], bfr[4];
      #pragma unroll
      for (int m = 0; m < 4; ++m)
        af[m] = *(const bf16x8*)&pl[wr * 64 + m * 16 + (lane & 15)][kk * 32 + (lane >> 4) * 8];
      #pragma unroll
      for (int n = 0; n < 4; ++n)
        bfr[n] = *(const bf16x8*)&cb[wc * 64 + n * 16 + (lane & 15)][kk * 32 + (lane >> 4) * 8];
      #pragma unroll
      for (int m = 0; m < 4; ++m)
        #pragma unroll
        for (int n = 0; n < 4; ++n)
          acc[m][n] = __builtin_amdgcn_mfma_f32_16x16x32_bf16(af[m], bfr[n], acc[m][n], 0, 0, 0);
    }
  }

  // epilogue: ob[b][n][h*D + f]
  #pragma unroll
  for (int m = 0; m < 4; ++m)
    #pragma unroll
    for (int n = 0; n < 4; ++n) {
      const int fc = h * D + wc * 64 + n * 16 + (lane & 15);
      #pragma unroll
      for (int r = 0; r < 4; ++r) {
        const int seq = b * S + j * BLK + half * 128 + wr * 64 + m * 16 + ro + r;
        ob[(size_t)seq * HD + fc] = f2bf(acc[m][n][r]);
      }
    }
}

// ---------------- RMSNorm * norm_w * sigmoid-gate -> bf16 ------------------
__global__ __launch_bounds__(256) void norm_gate(
    const unsigned short* __restrict__ ob, const unsigned short* __restrict__ gb,
    const float* __restrict__ nw, unsigned short* __restrict__ og) {
  const int row = blockIdx.x;
  const int t = threadIdx.x;
  const u16x8 ov = *(const u16x8*)&ob[(size_t)row * HD + t * 8];
  float f[8];
  float ss = 0.f;
  #pragma unroll
  for (int i = 0; i < 8; ++i) { f[i] = bf2f(ov[i]); ss += f[i] * f[i]; }
  #pragma unroll
  for (int off = 32; off > 0; off >>= 1) ss += __shfl_down(ss, off, 64);
  __shared__ float red[4];
  if ((t & 63) == 0) red[t >> 6] = ss;
  __syncthreads();
  const float rms = rsqrtf((red[0] + red[1] + red[2] + red[3]) * (1.f / HD) + 1e-6f);
  const u16x8 gv = *(const u16x8*)&gb[(size_t)row * HD + t * 8];
  u16x8 ow;
  #pragma unroll
  for (int i = 0; i < 8; ++i)
    ow[i] = f2bf(f[i] * rms * nw[t * 8 + i] * bf2f(gv[i]));
  *(u16x8*)&og[(size_t)row * HD + t * 8] = ow;
}

extern "C" void kernel_launch(void* const* d_in, const int* in_sizes, int n_in,
                              void* d_out, int out_size, void* d_ws, size_t ws_size,
                              hipStream_t stream) {
  (void)in_sizes; (void)n_in; (void)out_size; (void)ws_size;
  const float* x    = (const float*)d_in[0];
  const float* Wqkv = (const float*)d_in[1];
  const float* Wg   = (const float*)d_in[2];
  const float* Wout = (const float*)d_in[3];
  const float* nw   = (const float*)d_in[4];

  char* ws = (char*)d_ws;
  unsigned short* xb    = (unsigned short*)ws; ws += SZ_XB;
  unsigned short* wqkvt = (unsigned short*)ws; ws += SZ_WQKVT;
  unsigned short* wgt   = (unsigned short*)ws; ws += SZ_WGT;
  unsigned short* woutt = (unsigned short*)ws; ws += SZ_WOUTT;
  unsigned short* qkvb  = (unsigned short*)ws; ws += SZ_QKVB;
  unsigned short* gb    = (unsigned short*)ws; ws += SZ_GB;
  unsigned short* st    = (unsigned short*)ws; ws += SZ_ST;
  unsigned short* ob    = (unsigned short*)ws; ws += SZ_OB;
  unsigned short* og    = xb;  // alias: xb dead after the gate GEMM

  cvt_bf16<<<dim3((NB * S * DIN) / (256 * 8)), 256, 0, stream>>>(x, xb);
  transpose_cvt<<<dim3(NQKV / 32, DIN / 32), 256, 0, stream>>>(Wqkv, wqkvt, DIN, NQKV);
  transpose_cvt<<<dim3(HD / 32, DIN / 32), 256, 0, stream>>>(Wg, wgt, DIN, HD);
  transpose_cvt<<<dim3(HD / 32, HD / 32), 256, 0, stream>>>(Wout, woutt, HD, HD);

  // qkv = silu(x @ Wqkv), gate = sigmoid(x @ Wg)   [grids: 768 / 256 WGs, %8==0]
  gemm256<1><<<dim3((NB * S / 256) * (NQKV / 256)), 512, 0, stream>>>(xb, wqkvt, qkvb, NB * S, NQKV, DIN);
  gemm256<2><<<dim3((NB * S / 256) * (HD / 256)), 512, 0, stream>>>(xb, wgt, gb, NB * S, HD, DIN);

  kv_outer<<<dim3(NB * H * NBL), 256, 0, stream>>>(qkvb, st);
  kv_scan<<<dim3((NB * H * D * D) / 256), 256, 0, stream>>>(st);
  attn_mfma<<<dim3(NB * H * NBL * 2), 256, 0, stream>>>(qkvb, st, ob);

  norm_gate<<<dim3(NB * S), 256, 0, stream>>>(ob, gb, nw, og);
  gemm256<0><<<dim3((NB * S / 256) * (HD / 256)), 512, 0, stream>>>(og, woutt, d_out, NB * S, HD, HD);
}